// Round 11
// baseline (1415.873 us; speedup 1.0000x reference)
//
#include <hip/hip_runtime.h>
#include <hip/hip_bf16.h>
#include <stdint.h>

// B=8192, D_IN=1024, D_HID=4096, D_OUT=1024, E=8
#define BB 8192
#define DIN 1024
#define DHID 4096
#define DOUT 1024
#define NEXP 8
#define GH_N 2048  // D_HID/2

typedef __attribute__((ext_vector_type(8))) __bf16 bf16x8;
typedef __attribute__((ext_vector_type(4))) float f32x4;

__device__ inline unsigned short f2bf(float f) {
  unsigned u = __builtin_bit_cast(unsigned, f);
  u = (u + 0x7FFFu + ((u >> 16) & 1u)) >> 16;
  return (unsigned short)u;
}
__device__ inline float b2f(unsigned short s) {
  return __builtin_bit_cast(float, (unsigned)s << 16);
}

// ---------------- elementwise f32 -> bf16 ----------------
__global__ void cvt_f32_bf16(const float* __restrict__ in,
                             unsigned short* __restrict__ out, int n4) {
  int i = blockIdx.x * blockDim.x + threadIdx.x;
  if (i >= n4) return;
  float4 v = ((const float4*)in)[i];
  ushort4 o;
  o.x = f2bf(v.x); o.y = f2bf(v.y); o.z = f2bf(v.z); o.w = f2bf(v.w);
  ((ushort4*)out)[i] = o;
}

// ---- 64x64 transpose tile, 512 threads ----
__device__ inline void tr64(float (*tile)[65], const float* __restrict__ in,
                            unsigned short* __restrict__ out, int R, int C,
                            int bx, int by, int t) {
  const int c0 = bx * 64, r0 = by * 64;
  const int tx = t & 63, ty = t >> 6;  // ty 0..7
#pragma unroll
  for (int i = 0; i < 8; ++i) {
    int r = i * 8 + ty;
    tile[r][tx] = in[(size_t)(r0 + r) * C + c0 + tx];
  }
  __syncthreads();
#pragma unroll
  for (int i = 0; i < 8; ++i) {
    int r = i * 8 + ty;
    out[(size_t)(c0 + r) * R + r0 + tx] = f2bf(tile[tx][r]);
  }
  __syncthreads();
}

// gW1 [1024][2048] -> gW1T [2048][1024]   (512 tiles)
__global__ __launch_bounds__(512)
void trans_g(const float* __restrict__ gW1, unsigned short* __restrict__ gW1T) {
  __shared__ float tile[64][65];
  int b = blockIdx.x;
  tr64(tile, gW1, gW1T, DIN, GH_N, b & 31, b >> 5, threadIdx.x);
}

// per-expert: W1 [1024][4096]->w1T[4096][1024], W2 [4096][1024]->w2T[1024][4096]
__global__ __launch_bounds__(512)
void trans2(const float* __restrict__ w1, unsigned short* __restrict__ w1T,
            const float* __restrict__ w2, unsigned short* __restrict__ w2T) {
  __shared__ float tile[64][65];
  int b = blockIdx.x;
  if (b < 1024) {
    tr64(tile, w1, w1T, DIN, DHID, b & 63, b >> 6, threadIdx.x);
  } else {
    b -= 1024;
    tr64(tile, w2, w2T, DHID, DOUT, b & 15, b >> 4, threadIdx.x);
  }
}

// ---------------- async global->LDS 16B ----------------
__device__ inline void gload16(const void* g, void* l) {
  __builtin_amdgcn_global_load_lds(
      (const __attribute__((address_space(1))) void*)g,
      (__attribute__((address_space(3))) void*)l, 16, 0, 0);
}

template <int N>
__device__ inline void waitv() {
  if constexpr (N == 0) asm volatile("s_waitcnt vmcnt(0)" ::: "memory");
  else if constexpr (N == 2) asm volatile("s_waitcnt vmcnt(2)" ::: "memory");
  else if constexpr (N == 4) asm volatile("s_waitcnt vmcnt(4)" ::: "memory");
  else if constexpr (N == 6) asm volatile("s_waitcnt vmcnt(6)" ::: "memory");
  else asm volatile("s_waitcnt vmcnt(0)" ::: "memory");
}
__device__ inline void waitlgkm0() {
  asm volatile("s_waitcnt lgkmcnt(0)" ::: "memory");
  __builtin_amdgcn_sched_barrier(0);
}
__device__ inline bf16x8 ldr(const char* p) { return *(const bf16x8*)p; }

// ---------------- fat GEMM core: 256x256 tile, 4-phase, BK=64 --------------
// C = A[8192,K]*Bt[N,K]^T. 8 waves (2M x 4N), 2 LDS buffers, counted vmcnt.
// epi 0: outb = bf16(relu(acc+bias[col]))
// epi 2: outf (+)= gates[row*8+eidx]*(acc+bias[col])   (accum? add : store)
struct GA {
  const unsigned short* A;
  const unsigned short* Bt;
  int lda, ldb, N, K;
  const float* bias;
  unsigned short* outb;
  float* outf;
  const float* gates;
  int eidx, accum, nb, epi;
};

__device__ __forceinline__ void gemm_core(const GA& g, int local, char* lds) {
  char* Als = lds;
  char* Bls = lds + 65536;
  constexpr int ABYTES = 32768, BBYTES = 32768;
  const int t = threadIdx.x;
  const int lane = t & 63;
  const int wid = t >> 6;
  const int wm = wid >> 2;
  const int wn = wid & 3;
  const int l15 = lane & 15, lg = lane >> 4;

  const int nb = g.nb;
  const int swz = (local & 7) * (nb >> 3) + (local >> 3);
  const int nbn = g.N >> 8;
  const int bn = swz % nbn, bm = swz / nbn;
  const int m0 = bm * 256, n0 = bn * 256;

  const int prow = t >> 3;
  const int cOff = ((t & 7) ^ (prow & 7)) * 8;
  const unsigned short* aP[4];
  const unsigned short* bP[4];
#pragma unroll
  for (int u = 0; u < 4; ++u) {
    int p = u * 64 + prow;
    int ga = ((p >> 6) & 1) * 128 + ((p >> 7) & 1) * 64 + (p & 63);
    aP[u] = g.A + (size_t)(m0 + ga) * g.lda + cOff;
    int gb = ((p >> 5) & 3) * 64 + ((p >> 7) & 1) * 32 + (p & 31);
    bP[u] = g.Bt + (size_t)(n0 + gb) * g.ldb + cOff;
  }
  const int ldst = t * 16;

  const int slot0 = ((lg) ^ (l15 & 7)) * 16;
  const int slot1 = ((4 + lg) ^ (l15 & 7)) * 16;
  const int aRB0 = (wm * 64 + l15) * 128;
  const int aRB1 = (128 + wm * 64 + l15) * 128;
  const int bCB0 = (wn * 32 + l15) * 128;
  const int bCB1 = (128 + wn * 32 + l15) * 128;

  f32x4 acc[8][4];
  const f32x4 zero = {0.f, 0.f, 0.f, 0.f};
#pragma unroll
  for (int i = 0; i < 8; ++i)
#pragma unroll
    for (int j = 0; j < 4; ++j) acc[i][j] = zero;

  bf16x8 ar[4][2], bc0[2][2], bc1[2][2];
  const int NT = g.K >> 6;

  gload16(bP[0], Bls + 0 * 8192 + ldst);
  gload16(bP[1], Bls + 1 * 8192 + ldst);
  gload16(aP[0], Als + 0 * 8192 + ldst);
  gload16(aP[1], Als + 1 * 8192 + ldst);
  gload16(bP[2], Bls + 2 * 8192 + ldst);
  gload16(bP[3], Bls + 3 * 8192 + ldst);
  gload16(aP[2], Als + 2 * 8192 + ldst);
  gload16(aP[3], Als + 3 * 8192 + ldst);
  waitv<4>();
  __builtin_amdgcn_s_barrier();

  for (int T = 0; T < NT; ++T) {
    const int buf = T & 1;
    const char* Ab = Als + buf * ABYTES;
    const char* Bb = Bls + buf * BBYTES;
    char* An = Als + (buf ^ 1) * ABYTES;
    char* Bn = Bls + (buf ^ 1) * BBYTES;
    const bool stg = (T + 1 < NT);
    const int kn = (T + 1) << 6;

    // ph0
#pragma unroll
    for (int f = 0; f < 4; ++f) {
      ar[f][0] = ldr(Ab + aRB0 + f * 2048 + slot0);
      ar[f][1] = ldr(Ab + aRB0 + f * 2048 + slot1);
    }
#pragma unroll
    for (int c = 0; c < 2; ++c) {
      bc0[c][0] = ldr(Bb + bCB0 + c * 2048 + slot0);
      bc0[c][1] = ldr(Bb + bCB0 + c * 2048 + slot1);
    }
    if (stg) {
      gload16(bP[0] + kn, Bn + 0 * 8192 + ldst);
      gload16(bP[1] + kn, Bn + 1 * 8192 + ldst);
    }
    __builtin_amdgcn_s_barrier();
    waitlgkm0();
    __builtin_amdgcn_s_setprio(1);
#pragma unroll
    for (int ksl = 0; ksl < 2; ++ksl)
#pragma unroll
      for (int f = 0; f < 4; ++f)
#pragma unroll
        for (int c = 0; c < 2; ++c)
          acc[f][c] = __builtin_amdgcn_mfma_f32_16x16x32_bf16(
              ar[f][ksl], bc0[c][ksl], acc[f][c], 0, 0, 0);
    __builtin_amdgcn_s_setprio(0);
    if (stg) waitv<4>(); else waitv<2>();
    __builtin_amdgcn_s_barrier();

    // ph1
#pragma unroll
    for (int c = 0; c < 2; ++c) {
      bc1[c][0] = ldr(Bb + bCB1 + c * 2048 + slot0);
      bc1[c][1] = ldr(Bb + bCB1 + c * 2048 + slot1);
    }
    if (stg) {
      gload16(aP[0] + kn, An + 0 * 8192 + ldst);
      gload16(aP[1] + kn, An + 1 * 8192 + ldst);
    }
    __builtin_amdgcn_s_barrier();
    waitlgkm0();
    __builtin_amdgcn_s_setprio(1);
#pragma unroll
    for (int ksl = 0; ksl < 2; ++ksl)
#pragma unroll
      for (int f = 0; f < 4; ++f)
#pragma unroll
        for (int c = 0; c < 2; ++c)
          acc[f][2 + c] = __builtin_amdgcn_mfma_f32_16x16x32_bf16(
              ar[f][ksl], bc1[c][ksl], acc[f][2 + c], 0, 0, 0);
    __builtin_amdgcn_s_setprio(0);
    if (stg) waitv<4>(); else waitv<0>();
    __builtin_amdgcn_s_barrier();

    // ph2
#pragma unroll
    for (int f = 0; f < 4; ++f) {
      ar[f][0] = ldr(Ab + aRB1 + f * 2048 + slot0);
      ar[f][1] = ldr(Ab + aRB1 + f * 2048 + slot1);
    }
    if (stg) {
      gload16(bP[2] + kn, Bn + 2 * 8192 + ldst);
      gload16(bP[3] + kn, Bn + 3 * 8192 + ldst);
    }
    __builtin_amdgcn_s_barrier();
    waitlgkm0();
    __builtin_amdgcn_s_setprio(1);
#pragma unroll
    for (int ksl = 0; ksl < 2; ++ksl)
#pragma unroll
      for (int f = 0; f < 4; ++f)
#pragma unroll
        for (int c = 0; c < 2; ++c)
          acc[4 + f][2 + c] = __builtin_amdgcn_mfma_f32_16x16x32_bf16(
              ar[f][ksl], bc1[c][ksl], acc[4 + f][2 + c], 0, 0, 0);
    __builtin_amdgcn_s_setprio(0);
    __builtin_amdgcn_s_barrier();

    // ph3
    if (stg) {
      gload16(aP[2] + kn, An + 2 * 8192 + ldst);
      gload16(aP[3] + kn, An + 3 * 8192 + ldst);
    }
    __builtin_amdgcn_s_barrier();
    __builtin_amdgcn_s_setprio(1);
#pragma unroll
    for (int ksl = 0; ksl < 2; ++ksl)
#pragma unroll
      for (int f = 0; f < 4; ++f)
#pragma unroll
        for (int c = 0; c < 2; ++c)
          acc[4 + f][c] = __builtin_amdgcn_mfma_f32_16x16x32_bf16(
              ar[f][ksl], bc0[c][ksl], acc[4 + f][c], 0, 0, 0);
    __builtin_amdgcn_s_setprio(0);
    if (stg) waitv<4>();
    __builtin_amdgcn_s_barrier();
  }

  // epilogue: D row = lg*4 + reg (within 16), col = l15 (m89-verified)
  const int rb = m0 + wm * 128 + (lg << 2);
  const int cb = n0 + wn * 64 + l15;
  const int N = g.N;
  if (g.epi == 0) {
#pragma unroll
    for (int fg = 0; fg < 8; ++fg) {
#pragma unroll
      for (int j = 0; j < 4; ++j) {
        int col = cb + j * 16;
        float bv = g.bias[col];
#pragma unroll
        for (int r = 0; r < 4; ++r) {
          int row = rb + fg * 16 + r;
          float v = acc[fg][j][r] + bv;
          g.outb[(size_t)row * N + col] = f2bf(fmaxf(v, 0.f));
        }
      }
    }
  } else {  // epi 2: gated accumulate/store (one writer per element)
#pragma unroll
    for (int fg = 0; fg < 8; ++fg) {
      float gv[4];
#pragma unroll
      for (int r = 0; r < 4; ++r)
        gv[r] = g.gates[(size_t)(rb + fg * 16 + r) * NEXP + g.eidx];
#pragma unroll
      for (int j = 0; j < 4; ++j) {
        int col = cb + j * 16;
        float bv = g.bias[col];
#pragma unroll
        for (int r = 0; r < 4; ++r) {
          size_t o = (size_t)(rb + fg * 16 + r) * N + col;
          float v = (acc[fg][j][r] + bv) * gv[r];
          g.outf[o] = g.accum ? g.outf[o] + v : v;
        }
      }
    }
  }
}

// G1 / gating kernel: epi0 core + optional distributed pout merge
__global__ __launch_bounds__(512, 2)
void k_g1(GA g, const float4* __restrict__ mrgP, float4* __restrict__ mrgO) {
  __shared__ char lds[131072];
  gemm_core(g, blockIdx.x, lds);
  if (mrgP != nullptr) {
    size_t base = ((size_t)blockIdx.x * 512 + threadIdx.x) * 8;
#pragma unroll
    for (int i = 0; i < 8; ++i) {
      float4 p = mrgP[base + i];
      float4 o = mrgO[base + i];
      o.x += p.x; o.y += p.y; o.z += p.z; o.w += p.w;
      mrgO[base + i] = o;
    }
  }
}

// expert-pair G2: even blocks -> set0 (outC rmw), odd -> set1 (pout store)
__global__ __launch_bounds__(512, 2)
void k_g2pair(GA a0, GA a1) {
  __shared__ char lds[131072];
  const int set = blockIdx.x & 1;
  const GA& sel = set ? a1 : a0;
  gemm_core(sel, (int)blockIdx.x >> 1, lds);
}

// ---------------- gemmF: fallback G2 (128x256, 2 fat phases, 3-buf ring) ---
__global__ __launch_bounds__(512)
void gemmF(const unsigned short* __restrict__ A,
           const unsigned short* __restrict__ Bt,
           const float* __restrict__ bias,
           float* __restrict__ outC,
           const float* __restrict__ gates, int eidx, int accum) {
  constexpr int SLOT = 49152;
  __shared__ char lds[3 * SLOT];
  const int t = threadIdx.x;
  const int lane = t & 63;
  const int wid = t >> 6;
  const int wm = wid >> 2;
  const int wn = wid & 3;
  const int l15 = lane & 15, lg = lane >> 4;

  const int local = blockIdx.x;
  const int swz = (local & 7) * 32 + (local >> 3);
  const int bn = swz & 3, bm = swz >> 2;
  const int m0 = bm * 128, n0 = bn * 256;

  const int prow = t >> 3;
  const int cOff = ((t & 7) ^ (prow & 7)) * 8;
  const unsigned short* aP[2];
  const unsigned short* bP[4];
#pragma unroll
  for (int u = 0; u < 2; ++u)
    aP[u] = A + (size_t)(m0 + u * 64 + prow) * DHID + cOff;
#pragma unroll
  for (int u = 0; u < 4; ++u) {
    int p = u * 64 + prow;
    int gb = ((p >> 5) & 3) * 64 + ((p >> 7) & 1) * 32 + (p & 31);
    bP[u] = Bt + (size_t)(n0 + gb) * DHID + cOff;
  }
  const int ldst = t * 16;

  const int slot0 = ((lg) ^ (l15 & 7)) * 16;
  const int slot1 = ((4 + lg) ^ (l15 & 7)) * 16;
  const int aRB = (wm * 64 + l15) * 128;
  const int bCB0 = 16384 + (wn * 32 + l15) * 128;
  const int bCB1 = 16384 + (128 + wn * 32 + l15) * 128;

  f32x4 acc[4][4];
  const f32x4 zero = {0.f, 0.f, 0.f, 0.f};
#pragma unroll
  for (int i = 0; i < 4; ++i)
#pragma unroll
    for (int j = 0; j < 4; ++j) acc[i][j] = zero;

  bf16x8 af[2][2], bc[4][2];
  const int NT = DHID >> 6;

#pragma unroll
  for (int T0 = 0; T0 < 2; ++T0) {
    char* S = lds + T0 * SLOT;
    const int k0 = T0 << 6;
    gload16(aP[0] + k0, S + 0 * 8192 + ldst);
    gload16(aP[1] + k0, S + 1 * 8192 + ldst);
    gload16(bP[0] + k0, S + 16384 + 0 * 8192 + ldst);
    gload16(bP[1] + k0, S + 16384 + 1 * 8192 + ldst);
    gload16(bP[2] + k0, S + 16384 + 2 * 8192 + ldst);
    gload16(bP[3] + k0, S + 16384 + 3 * 8192 + ldst);
  }
  waitv<6>();
  __builtin_amdgcn_s_barrier();

  for (int T = 0; T < NT; ++T) {
    const char* Sb = lds + (T % 3) * SLOT;
    char* Sn = lds + ((T + 2) % 3) * SLOT;
    const bool stg = (T + 2 < NT);
    const int kn = (T + 2) << 6;

    // ph0
#pragma unroll
    for (int f = 0; f < 2; ++f) {
      af[f][0] = ldr(Sb + aRB + f * 2048 + slot0);
      af[f][1] = ldr(Sb + aRB + f * 2048 + slot1);
    }
#pragma unroll
    for (int c = 0; c < 2; ++c) {
      bc[c][0] = ldr(Sb + bCB0 + c * 2048 + slot0);
      bc[c][1] = ldr(Sb + bCB0 + c * 2048 + slot1);
      bc[2 + c][0] = ldr(Sb + bCB1 + c * 2048 + slot0);
      bc[2 + c][1] = ldr(Sb + bCB1 + c * 2048 + slot1);
    }
    if (stg) {
      gload16(aP[0] + kn, Sn + 0 * 8192 + ldst);
      gload16(aP[1] + kn, Sn + 1 * 8192 + ldst);
      gload16(bP[0] + kn, Sn + 16384 + 0 * 8192 + ldst);
    }
    __builtin_amdgcn_s_barrier();
    waitlgkm0();
    __builtin_amdgcn_s_setprio(1);
#pragma unroll
    for (int ksl = 0; ksl < 2; ++ksl)
#pragma unroll
      for (int f = 0; f < 2; ++f)
#pragma unroll
        for (int c = 0; c < 4; ++c)
          acc[f][c] = __builtin_amdgcn_mfma_f32_16x16x32_bf16(
              af[f][ksl], bc[c][ksl], acc[f][c], 0, 0, 0);
    __builtin_amdgcn_s_setprio(0);
    __builtin_amdgcn_s_barrier();

    // ph1
#pragma unroll
    for (int f = 0; f < 2; ++f) {
      af[f][0] = ldr(Sb + aRB + (2 + f) * 2048 + slot0);
      af[f][1] = ldr(Sb + aRB + (2 + f) * 2048 + slot1);
    }
    if (stg) {
      gload16(bP[1] + kn, Sn + 16384 + 1 * 8192 + ldst);
      gload16(bP[2] + kn, Sn + 16384 + 2 * 8192 + ldst);
      gload16(bP[3] + kn, Sn + 16384 + 3 * 8192 + ldst);
    }
    __builtin_amdgcn_s_barrier();
    waitlgkm0();
    __builtin_amdgcn_s_setprio(1);
#pragma unroll
    for (int ksl = 0; ksl < 2; ++ksl)
#pragma unroll
      for (int f = 0; f < 2; ++f)
#pragma unroll
        for (int c = 0; c < 4; ++c)
          acc[2 + f][c] = __builtin_amdgcn_mfma_f32_16x16x32_bf16(
              af[f][ksl], bc[c][ksl], acc[2 + f][c], 0, 0, 0);
    __builtin_amdgcn_s_setprio(0);
    if (stg) waitv<6>();
    else if (T + 1 < NT) waitv<0>();
    __builtin_amdgcn_s_barrier();
  }

  const int rb = m0 + wm * 64 + (lg << 2);
  const int cb = n0 + wn * 64 + l15;
#pragma unroll
  for (int fg = 0; fg < 4; ++fg) {
    float gv[4];
#pragma unroll
    for (int r = 0; r < 4; ++r)
      gv[r] = gates[(size_t)(rb + fg * 16 + r) * NEXP + eidx];
#pragma unroll
    for (int j = 0; j < 4; ++j) {
      int col = cb + j * 16;
      float bv = bias[col];
#pragma unroll
      for (int r = 0; r < 4; ++r) {
        size_t o = (size_t)(rb + fg * 16 + r) * DOUT + col;
        float v = (acc[fg][j][r] + bv) * gv[r];
        outC[o] = accum ? outC[o] + v : v;
      }
    }
  }
}

// ---------------- final merge: outC += pout ----------------
__global__ void merge_final(const float4* __restrict__ p,
                            float4* __restrict__ o) {
  size_t i = (size_t)blockIdx.x * 256 + threadIdx.x;
  float4 a = p[i], b = o[i];
  b.x += a.x; b.y += a.y; b.z += a.z; b.w += a.w;
  o[i] = b;
}

// ---------------- gating head ----------------
__global__ __launch_bounds__(512)
void gating_head2(const unsigned short* __restrict__ gh,
                  const float* __restrict__ gW2,
                  const float* __restrict__ gb2,
                  float* __restrict__ gws,
                  float* __restrict__ g1,
                  float* __restrict__ g2) {
  __shared__ float wT[8][2048];
  const int t = threadIdx.x;
  for (int idx = t; idx < 16384; idx += 512) {
    wT[idx & 7][idx >> 3] = gW2[idx];
  }
  __syncthreads();
  const int wid = t >> 6, lane = t & 63;
  const int row = blockIdx.x * 8 + wid;
  const unsigned short* ghr = gh + (size_t)row * 2048;
  float s[8] = {0.f, 0.f, 0.f, 0.f, 0.f, 0.f, 0.f, 0.f};
#pragma unroll
  for (int j = 0; j < 8; ++j) {
    int k4 = lane + 64 * j;
    ushort4 hv = ((const ushort4*)ghr)[k4];
    float h0 = b2f(hv.x), h1 = b2f(hv.y), h2 = b2f(hv.z), h3 = b2f(hv.w);
#pragma unroll
    for (int e = 0; e < 8; ++e) {
      float4 w = ((const float4*)&wT[e][0])[k4];
      s[e] += h0 * w.x + h1 * w.y + h2 * w.z + h3 * w.w;
    }
  }
#pragma unroll
  for (int e = 0; e < 8; ++e)
#pragma unroll
    for (int off = 1; off < 64; off <<= 1) s[e] += __shfl_xor(s[e], off, 64);
  if (lane == 0) {
    float l[8], m = -1e30f;
#pragma unroll
    for (int e = 0; e < 8; ++e) {
      l[e] = s[e] + gb2[e];
      m = fmaxf(m, l[e]);
    }
    float sum = 0.f;
#pragma unroll
    for (int e = 0; e < 8; ++e) {
      l[e] = expf(l[e] - m);
      sum += l[e];
    }
    float inv = 1.f / sum;
#pragma unroll
    for (int e = 0; e < 8; ++e) {
      float gv = l[e] * inv;
      gws[(size_t)row * 8 + e] = gv;
      g1[(size_t)row * 8 + e] = gv;
      g2[(size_t)row * 8 + e] = gv;
    }
  }
}

extern "C" void kernel_launch(void* const* d_in, const int* in_sizes, int n_in,
                              void* d_out, int out_size, void* d_ws,
                              size_t ws_size, hipStream_t stream) {
  (void)in_sizes; (void)n_in; (void)out_size;
  const float* x   = (const float*)d_in[0];
  const float* gW1 = (const float*)d_in[1];
  const float* gb1 = (const float*)d_in[2];
  const float* gW2 = (const float*)d_in[3];
  const float* gb2 = (const float*)d_in[4];
  const float* eW1 = (const float*)d_in[5];
  const float* eb1 = (const float*)d_in[6];
  const float* eW2 = (const float*)d_in[7];
  const float* eb2 = (const float*)d_in[8];

  float* outC  = (float*)d_out;                       // [8192,1024]
  float* outG1 = outC + (size_t)BB * DOUT;            // [8192,8]
  float* outG2 = outG1 + (size_t)BB * NEXP;           // [8192,8]

  char* ws = (char*)d_ws;
  const bool pairpath = ws_size >= (size_t)209977344;

  if (pairpath) {
    // layout: 209,977,344 B
    unsigned short* xb   = (unsigned short*)(ws);              // 16 MB
    float*          gat  = (float*)(ws + 16777216);            // 256 KB
    unsigned short* w1s  = (unsigned short*)(ws + 17039360);   // 8 MB (shared)
    unsigned short* w2A  = (unsigned short*)(ws + 25427968);   // 8 MB
    unsigned short* w2B  = (unsigned short*)(ws + 33816576);   // 8 MB
    unsigned short* hA   = (unsigned short*)(ws + 42205184);   // 64 MB
    unsigned short* hB   = (unsigned short*)(ws + 109314048);  // 64 MB
    float*          pout = (float*)(ws + 176422912);           // 32 MB
    unsigned short* gh   = hA;   // pre-loop alias
    unsigned short* gW1T = hB;   // pre-loop alias

    cvt_f32_bf16<<<(BB * DIN / 4) / 256, 256, 0, stream>>>(x, xb, BB * DIN / 4);
    trans_g<<<512, 512, 0, stream>>>(gW1, gW1T);
    {
      GA a{xb, gW1T, DIN, DIN, GH_N, DIN, gb1, gh, nullptr, nullptr, 0, 0, 256, 0};
      k_g1<<<256, 512, 0, stream>>>(a, nullptr, nullptr);
    }
    gating_head2<<<BB / 8, 512, 0, stream>>>(gh, gW2, gb2, gat, outG1, outG2);

    for (int p = 0; p < 4; ++p) {
      const int e0 = 2 * p, e1 = 2 * p + 1;
      // T(e0) -> w1s, w2A
      trans2<<<2048, 512, 0, stream>>>(
          eW1 + (size_t)e0 * DIN * DHID, w1s, eW2 + (size_t)e0 * DHID * DOUT, w2A);
      // G1(e0) -> hA  (+ merge of previous pair's pout into outC)
      {
        GA a{xb, w1s, DIN, DIN, DHID, DIN, eb1 + (size_t)e0 * DHID,
             hA, nullptr, nullptr, 0, 0, 512, 0};
        k_g1<<<512, 512, 0, stream>>>(
            a, p > 0 ? (const float4*)pout : nullptr, (float4*)outC);
      }
      // T(e1) -> w1s, w2B
      trans2<<<2048, 512, 0, stream>>>(
          eW1 + (size_t)e1 * DIN * DHID, w1s, eW2 + (size_t)e1 * DHID * DOUT, w2B);
      // G1(e1) -> hB
      {
        GA a{xb, w1s, DIN, DIN, DHID, DIN, eb1 + (size_t)e1 * DHID,
             hB, nullptr, nullptr, 0, 0, 512, 0};
        k_g1<<<512, 512, 0, stream>>>(a, nullptr, nullptr);
      }
      // G2 pair: 256 fat blocks full chip.
      // set0 (even blocks): outC (+)= g_e0*(hA@w2A + eb2_e0)
      // set1 (odd blocks):  pout  =  g_e1*(hB@w2B + eb2_e1)
      {
        GA a0{hA, w2A, DHID, DHID, DOUT, DHID, eb2 + (size_t)e0 * DOUT,
              nullptr, outC, gat, e0, p > 0 ? 1 : 0, 128, 2};
        GA a1{hB, w2B, DHID, DHID, DOUT, DHID, eb2 + (size_t)e1 * DOUT,
              nullptr, pout, gat, e1, 0, 128, 2};
        k_g2pair<<<256, 512, 0, stream>>>(a0, a1);
      }
    }
    // fold last pair's set1 partial
    merge_final<<<BB, 256, 0, stream>>>((const float4*)pout, (float4*)outC);
  } else {
    // ---- fallback: r8 structure (proven 1343 us) ----
    unsigned short* xb   = (unsigned short*)(ws);               // 16 MB
    float*          gat  = (float*)(ws + 16777216);             // 256 KB
    unsigned short* w1T  = (unsigned short*)(ws + 17039360);    // 8 MB
    unsigned short* w2T  = (unsigned short*)(ws + 25427968);    // 8 MB
    unsigned short* hbuf = (unsigned short*)(ws + 33816576);    // 64 MB
    unsigned short* gh   = hbuf;
    unsigned short* gW1T = w1T;

    cvt_f32_bf16<<<(BB * DIN / 4) / 256, 256, 0, stream>>>(x, xb, BB * DIN / 4);
    trans_g<<<512, 512, 0, stream>>>(gW1, gW1T);
    {
      GA a{xb, gW1T, DIN, DIN, GH_N, DIN, gb1, gh, nullptr, nullptr, 0, 0, 256, 0};
      k_g1<<<256, 512, 0, stream>>>(a, nullptr, nullptr);
    }
    gating_head2<<<BB / 8, 512, 0, stream>>>(gh, gW2, gb2, gat, outG1, outG2);

    for (int e = 0; e < NEXP; ++e) {
      trans2<<<2048, 512, 0, stream>>>(
          eW1 + (size_t)e * DIN * DHID, w1T, eW2 + (size_t)e * DHID * DOUT, w2T);
      {
        GA a{xb, w1T, DIN, DIN, DHID, DIN, eb1 + (size_t)e * DHID,
             hbuf, nullptr, nullptr, 0, 0, 512, 0};
        k_g1<<<512, 512, 0, stream>>>(a, nullptr, nullptr);
      }
      gemmF<<<256, 512, 0, stream>>>(hbuf, w2T, eb2 + (size_t)e * DOUT, outC,
                                     gat, e, e > 0 ? 1 : 0);
    }
  }
}

// Round 12
// 1394.416 us; speedup vs baseline: 1.0154x; 1.0154x over previous
//
#include <hip/hip_runtime.h>
#include <hip/hip_bf16.h>
#include <stdint.h>

// B=8192, D_IN=1024, D_HID=4096, D_OUT=1024, E=8
#define BB 8192
#define DIN 1024
#define DHID 4096
#define DOUT 1024
#define NEXP 8
#define GH_N 2048  // D_HID/2

typedef __attribute__((ext_vector_type(8))) __bf16 bf16x8;
typedef __attribute__((ext_vector_type(4))) float f32x4;

__device__ inline unsigned short f2bf(float f) {
  unsigned u = __builtin_bit_cast(unsigned, f);
  u = (u + 0x7FFFu + ((u >> 16) & 1u)) >> 16;
  return (unsigned short)u;
}
__device__ inline float b2f(unsigned short s) {
  return __builtin_bit_cast(float, (unsigned)s << 16);
}

// ---------------- elementwise f32 -> bf16 ----------------
__global__ void cvt_f32_bf16(const float* __restrict__ in,
                             unsigned short* __restrict__ out, int n4) {
  int i = blockIdx.x * blockDim.x + threadIdx.x;
  if (i >= n4) return;
  float4 v = ((const float4*)in)[i];
  ushort4 o;
  o.x = f2bf(v.x); o.y = f2bf(v.y); o.z = f2bf(v.z); o.w = f2bf(v.w);
  ((ushort4*)out)[i] = o;
}

// ---- 128x64 transpose tile, 512 threads: full 256B read AND write segments
// in[R][C] f32, rows [by*128,+128) x cols [bx*64,+64)  ->  out[C][R] bf16
__device__ inline void tr128(const float* __restrict__ in,
                             unsigned short* __restrict__ out, int R, int C,
                             int bx, int by, int t) {
  __shared__ float tile[128][65];
  const int c0 = bx * 64, r0 = by * 128;
  const int tx = t & 63, ty = t >> 6;  // read: 64-lane rows, 8 rows/iter
#pragma unroll
  for (int i = 0; i < 16; ++i) {
    int r = i * 8 + ty;
    tile[r][tx] = in[(size_t)(r0 + r) * C + c0 + tx];
  }
  __syncthreads();
  const int tx2 = t & 127, ty2 = t >> 7;  // write: 128-lane rows (256B bf16)
#pragma unroll
  for (int i = 0; i < 16; ++i) {
    int cc = i * 4 + ty2;
    out[(size_t)(c0 + cc) * R + r0 + tx2] = f2bf(tile[tx2][cc]);
  }
}

// gW1 [1024][2048] -> gW1T [2048][1024]   (8 x 32 = 256 blocks)
__global__ __launch_bounds__(512)
void trans_g(const float* __restrict__ gW1, unsigned short* __restrict__ gW1T) {
  int b = blockIdx.x;
  tr128(gW1, gW1T, DIN, GH_N, b & 31, b >> 5, threadIdx.x);
}

// per-expert: eW1 [1024][4096]->w1T (8x64=512 blocks), eW2 [4096][1024]->w2T
// (32x16=512 blocks). grid 1024.
__global__ __launch_bounds__(512)
void trans2(const float* __restrict__ w1, unsigned short* __restrict__ w1T,
            const float* __restrict__ w2, unsigned short* __restrict__ w2T) {
  int b = blockIdx.x;
  if (b < 512) {
    tr128(w1, w1T, DIN, DHID, b & 63, b >> 6, threadIdx.x);
  } else {
    b -= 512;
    tr128(w2, w2T, DHID, DOUT, b & 15, b >> 4, threadIdx.x);
  }
}

// ---------------- async global->LDS 16B ----------------
__device__ inline void gload16(const void* g, void* l) {
  __builtin_amdgcn_global_load_lds(
      (const __attribute__((address_space(1))) void*)g,
      (__attribute__((address_space(3))) void*)l, 16, 0, 0);
}

template <int N>
__device__ inline void waitv() {
  if constexpr (N == 0) asm volatile("s_waitcnt vmcnt(0)" ::: "memory");
  else if constexpr (N == 2) asm volatile("s_waitcnt vmcnt(2)" ::: "memory");
  else if constexpr (N == 4) asm volatile("s_waitcnt vmcnt(4)" ::: "memory");
  else if constexpr (N == 6) asm volatile("s_waitcnt vmcnt(6)" ::: "memory");
  else asm volatile("s_waitcnt vmcnt(0)" ::: "memory");
}
__device__ inline void waitlgkm0() {
  asm volatile("s_waitcnt lgkmcnt(0)" ::: "memory");
  __builtin_amdgcn_sched_barrier(0);
}
__device__ inline bf16x8 ldr(const char* p) { return *(const bf16x8*)p; }

// ---------------- gemmU: 256x256 fat 4-phase (proven ~1270 TF) -------------
// C = A[8192,K]*Bt[N,K]^T, epi: outb = bf16(relu(acc+bias[col]))
struct GArgs {
  const unsigned short* A;
  const unsigned short* Bt;
  int lda, ldb, N, K;
  const float* bias;
  unsigned short* outb;
  int nb;
};

__global__ __launch_bounds__(512, 2)
void gemmU(GArgs g) {
  __shared__ char lds[131072];
  char* Als = lds;
  char* Bls = lds + 65536;
  constexpr int ABYTES = 32768, BBYTES = 32768;
  const int t = threadIdx.x;
  const int lane = t & 63;
  const int wid = t >> 6;
  const int wm = wid >> 2;
  const int wn = wid & 3;
  const int l15 = lane & 15, lg = lane >> 4;

  const int nb = g.nb;
  const int local = blockIdx.x;
  const int swz = (local & 7) * (nb >> 3) + (local >> 3);
  const int nbn = g.N >> 8;
  const int bn = swz % nbn, bm = swz / nbn;
  const int m0 = bm * 256, n0 = bn * 256;

  const int prow = t >> 3;
  const int cOff = ((t & 7) ^ (prow & 7)) * 8;
  const unsigned short* aP[4];
  const unsigned short* bP[4];
#pragma unroll
  for (int u = 0; u < 4; ++u) {
    int p = u * 64 + prow;
    int ga = ((p >> 6) & 1) * 128 + ((p >> 7) & 1) * 64 + (p & 63);
    aP[u] = g.A + (size_t)(m0 + ga) * g.lda + cOff;
    int gb = ((p >> 5) & 3) * 64 + ((p >> 7) & 1) * 32 + (p & 31);
    bP[u] = g.Bt + (size_t)(n0 + gb) * g.ldb + cOff;
  }
  const int ldst = t * 16;

  const int slot0 = ((lg) ^ (l15 & 7)) * 16;
  const int slot1 = ((4 + lg) ^ (l15 & 7)) * 16;
  const int aRB0 = (wm * 64 + l15) * 128;
  const int aRB1 = (128 + wm * 64 + l15) * 128;
  const int bCB0 = (wn * 32 + l15) * 128;
  const int bCB1 = (128 + wn * 32 + l15) * 128;

  f32x4 acc[8][4];
  const f32x4 zero = {0.f, 0.f, 0.f, 0.f};
#pragma unroll
  for (int i = 0; i < 8; ++i)
#pragma unroll
    for (int j = 0; j < 4; ++j) acc[i][j] = zero;

  bf16x8 ar[4][2], bc0[2][2], bc1[2][2];
  const int NT = g.K >> 6;

  gload16(bP[0], Bls + 0 * 8192 + ldst);
  gload16(bP[1], Bls + 1 * 8192 + ldst);
  gload16(aP[0], Als + 0 * 8192 + ldst);
  gload16(aP[1], Als + 1 * 8192 + ldst);
  gload16(bP[2], Bls + 2 * 8192 + ldst);
  gload16(bP[3], Bls + 3 * 8192 + ldst);
  gload16(aP[2], Als + 2 * 8192 + ldst);
  gload16(aP[3], Als + 3 * 8192 + ldst);
  waitv<4>();
  __builtin_amdgcn_s_barrier();

  for (int T = 0; T < NT; ++T) {
    const int buf = T & 1;
    const char* Ab = Als + buf * ABYTES;
    const char* Bb = Bls + buf * BBYTES;
    char* An = Als + (buf ^ 1) * ABYTES;
    char* Bn = Bls + (buf ^ 1) * BBYTES;
    const bool stg = (T + 1 < NT);
    const int kn = (T + 1) << 6;

    // ph0
#pragma unroll
    for (int f = 0; f < 4; ++f) {
      ar[f][0] = ldr(Ab + aRB0 + f * 2048 + slot0);
      ar[f][1] = ldr(Ab + aRB0 + f * 2048 + slot1);
    }
#pragma unroll
    for (int c = 0; c < 2; ++c) {
      bc0[c][0] = ldr(Bb + bCB0 + c * 2048 + slot0);
      bc0[c][1] = ldr(Bb + bCB0 + c * 2048 + slot1);
    }
    if (stg) {
      gload16(bP[0] + kn, Bn + 0 * 8192 + ldst);
      gload16(bP[1] + kn, Bn + 1 * 8192 + ldst);
    }
    __builtin_amdgcn_s_barrier();
    waitlgkm0();
    __builtin_amdgcn_s_setprio(1);
#pragma unroll
    for (int ksl = 0; ksl < 2; ++ksl)
#pragma unroll
      for (int f = 0; f < 4; ++f)
#pragma unroll
        for (int c = 0; c < 2; ++c)
          acc[f][c] = __builtin_amdgcn_mfma_f32_16x16x32_bf16(
              ar[f][ksl], bc0[c][ksl], acc[f][c], 0, 0, 0);
    __builtin_amdgcn_s_setprio(0);
    if (stg) waitv<4>(); else waitv<2>();
    __builtin_amdgcn_s_barrier();

    // ph1
#pragma unroll
    for (int c = 0; c < 2; ++c) {
      bc1[c][0] = ldr(Bb + bCB1 + c * 2048 + slot0);
      bc1[c][1] = ldr(Bb + bCB1 + c * 2048 + slot1);
    }
    if (stg) {
      gload16(aP[0] + kn, An + 0 * 8192 + ldst);
      gload16(aP[1] + kn, An + 1 * 8192 + ldst);
    }
    __builtin_amdgcn_s_barrier();
    waitlgkm0();
    __builtin_amdgcn_s_setprio(1);
#pragma unroll
    for (int ksl = 0; ksl < 2; ++ksl)
#pragma unroll
      for (int f = 0; f < 4; ++f)
#pragma unroll
        for (int c = 0; c < 2; ++c)
          acc[f][2 + c] = __builtin_amdgcn_mfma_f32_16x16x32_bf16(
              ar[f][ksl], bc1[c][ksl], acc[f][2 + c], 0, 0, 0);
    __builtin_amdgcn_s_setprio(0);
    if (stg) waitv<4>(); else waitv<0>();
    __builtin_amdgcn_s_barrier();

    // ph2
#pragma unroll
    for (int f = 0; f < 4; ++f) {
      ar[f][0] = ldr(Ab + aRB1 + f * 2048 + slot0);
      ar[f][1] = ldr(Ab + aRB1 + f * 2048 + slot1);
    }
    if (stg) {
      gload16(bP[2] + kn, Bn + 2 * 8192 + ldst);
      gload16(bP[3] + kn, Bn + 3 * 8192 + ldst);
    }
    __builtin_amdgcn_s_barrier();
    waitlgkm0();
    __builtin_amdgcn_s_setprio(1);
#pragma unroll
    for (int ksl = 0; ksl < 2; ++ksl)
#pragma unroll
      for (int f = 0; f < 4; ++f)
#pragma unroll
        for (int c = 0; c < 2; ++c)
          acc[4 + f][2 + c] = __builtin_amdgcn_mfma_f32_16x16x32_bf16(
              ar[f][ksl], bc1[c][ksl], acc[4 + f][2 + c], 0, 0, 0);
    __builtin_amdgcn_s_setprio(0);
    __builtin_amdgcn_s_barrier();

    // ph3
    if (stg) {
      gload16(aP[2] + kn, An + 2 * 8192 + ldst);
      gload16(aP[3] + kn, An + 3 * 8192 + ldst);
    }
    __builtin_amdgcn_s_barrier();
    __builtin_amdgcn_s_setprio(1);
#pragma unroll
    for (int ksl = 0; ksl < 2; ++ksl)
#pragma unroll
      for (int f = 0; f < 4; ++f)
#pragma unroll
        for (int c = 0; c < 2; ++c)
          acc[4 + f][c] = __builtin_amdgcn_mfma_f32_16x16x32_bf16(
              ar[f][ksl], bc0[c][ksl], acc[4 + f][c], 0, 0, 0);
    __builtin_amdgcn_s_setprio(0);
    if (stg) waitv<4>();
    __builtin_amdgcn_s_barrier();
  }

  const int rb = m0 + wm * 128 + (lg << 2);
  const int cb = n0 + wn * 64 + l15;
  const int N = g.N;
#pragma unroll
  for (int fg = 0; fg < 8; ++fg) {
#pragma unroll
    for (int j = 0; j < 4; ++j) {
      int col = cb + j * 16;
      float bv = g.bias[col];
#pragma unroll
      for (int r = 0; r < 4; ++r) {
        int row = rb + fg * 16 + r;
        float v = acc[fg][j][r] + bv;
        g.outb[(size_t)row * N + col] = f2bf(fmaxf(v, 0.f));
      }
    }
  }
}

// ---------------- gemmF: G2 engine (128x256, 2 fat phases, 3-buf ring) -----
// K-skew: each block starts its K loop at tile (swz & 63) -- spreads hbuf
// streaming across the address space (per-block sum order fixed -> determ.)
__global__ __launch_bounds__(512)
void gemmF(const unsigned short* __restrict__ A,
           const unsigned short* __restrict__ Bt,
           const float* __restrict__ bias,
           float* __restrict__ outC,
           const float* __restrict__ gates, int eidx, int accum) {
  constexpr int SLOT = 49152;
  __shared__ char lds[3 * SLOT];
  const int t = threadIdx.x;
  const int lane = t & 63;
  const int wid = t >> 6;
  const int wm = wid >> 2;
  const int wn = wid & 3;
  const int l15 = lane & 15, lg = lane >> 4;

  const int local = blockIdx.x;
  const int swz = (local & 7) * 32 + (local >> 3);
  const int bn = swz & 3, bm = swz >> 2;
  const int m0 = bm * 128, n0 = bn * 256;
  const int kSkew = swz & 63;  // K-start rotation (NT=64)

  const int prow = t >> 3;
  const int cOff = ((t & 7) ^ (prow & 7)) * 8;
  const unsigned short* aP[2];
  const unsigned short* bP[4];
#pragma unroll
  for (int u = 0; u < 2; ++u)
    aP[u] = A + (size_t)(m0 + u * 64 + prow) * DHID + cOff;
#pragma unroll
  for (int u = 0; u < 4; ++u) {
    int p = u * 64 + prow;
    int gb = ((p >> 5) & 3) * 64 + ((p >> 7) & 1) * 32 + (p & 31);
    bP[u] = Bt + (size_t)(n0 + gb) * DHID + cOff;
  }
  const int ldst = t * 16;

  const int slot0 = ((lg) ^ (l15 & 7)) * 16;
  const int slot1 = ((4 + lg) ^ (l15 & 7)) * 16;
  const int aRB = (wm * 64 + l15) * 128;
  const int bCB0 = 16384 + (wn * 32 + l15) * 128;
  const int bCB1 = 16384 + (128 + wn * 32 + l15) * 128;

  f32x4 acc[4][4];
  const f32x4 zero = {0.f, 0.f, 0.f, 0.f};
#pragma unroll
  for (int i = 0; i < 4; ++i)
#pragma unroll
    for (int j = 0; j < 4; ++j) acc[i][j] = zero;

  bf16x8 af[2][2], bc[4][2];
  const int NT = DHID >> 6;  // 64

#pragma unroll
  for (int T0 = 0; T0 < 2; ++T0) {
    char* S = lds + T0 * SLOT;
    const int k0 = ((T0 + kSkew) & 63) << 6;
    gload16(aP[0] + k0, S + 0 * 8192 + ldst);
    gload16(aP[1] + k0, S + 1 * 8192 + ldst);
    gload16(bP[0] + k0, S + 16384 + 0 * 8192 + ldst);
    gload16(bP[1] + k0, S + 16384 + 1 * 8192 + ldst);
    gload16(bP[2] + k0, S + 16384 + 2 * 8192 + ldst);
    gload16(bP[3] + k0, S + 16384 + 3 * 8192 + ldst);
  }
  waitv<6>();
  __builtin_amdgcn_s_barrier();

  for (int T = 0; T < NT; ++T) {
    const char* Sb = lds + (T % 3) * SLOT;
    char* Sn = lds + ((T + 2) % 3) * SLOT;
    const bool stg = (T + 2 < NT);
    const int kn = ((T + 2 + kSkew) & 63) << 6;

    // ph0
#pragma unroll
    for (int f = 0; f < 2; ++f) {
      af[f][0] = ldr(Sb + aRB + f * 2048 + slot0);
      af[f][1] = ldr(Sb + aRB + f * 2048 + slot1);
    }
#pragma unroll
    for (int c = 0; c < 2; ++c) {
      bc[c][0] = ldr(Sb + bCB0 + c * 2048 + slot0);
      bc[c][1] = ldr(Sb + bCB0 + c * 2048 + slot1);
      bc[2 + c][0] = ldr(Sb + bCB1 + c * 2048 + slot0);
      bc[2 + c][1] = ldr(Sb + bCB1 + c * 2048 + slot1);
    }
    if (stg) {
      gload16(aP[0] + kn, Sn + 0 * 8192 + ldst);
      gload16(aP[1] + kn, Sn + 1 * 8192 + ldst);
      gload16(bP[0] + kn, Sn + 16384 + 0 * 8192 + ldst);
    }
    __builtin_amdgcn_s_barrier();
    waitlgkm0();
    __builtin_amdgcn_s_setprio(1);
#pragma unroll
    for (int ksl = 0; ksl < 2; ++ksl)
#pragma unroll
      for (int f = 0; f < 2; ++f)
#pragma unroll
        for (int c = 0; c < 4; ++c)
          acc[f][c] = __builtin_amdgcn_mfma_f32_16x16x32_bf16(
              af[f][ksl], bc[c][ksl], acc[f][c], 0, 0, 0);
    __builtin_amdgcn_s_setprio(0);
    __builtin_amdgcn_s_barrier();

    // ph1
#pragma unroll
    for (int f = 0; f < 2; ++f) {
      af[f][0] = ldr(Sb + aRB + (2 + f) * 2048 + slot0);
      af[f][1] = ldr(Sb + aRB + (2 + f) * 2048 + slot1);
    }
    if (stg) {
      gload16(bP[1] + kn, Sn + 16384 + 1 * 8192 + ldst);
      gload16(bP[2] + kn, Sn + 16384 + 2 * 8192 + ldst);
      gload16(bP[3] + kn, Sn + 16384 + 3 * 8192 + ldst);
    }
    __builtin_amdgcn_s_barrier();
    waitlgkm0();
    __builtin_amdgcn_s_setprio(1);
#pragma unroll
    for (int ksl = 0; ksl < 2; ++ksl)
#pragma unroll
      for (int f = 0; f < 2; ++f)
#pragma unroll
        for (int c = 0; c < 4; ++c)
          acc[2 + f][c] = __builtin_amdgcn_mfma_f32_16x16x32_bf16(
              af[f][ksl], bc[c][ksl], acc[2 + f][c], 0, 0, 0);
    __builtin_amdgcn_s_setprio(0);
    if (stg) waitv<6>();
    else if (T + 1 < NT) waitv<0>();
    __builtin_amdgcn_s_barrier();
  }

  const int rb = m0 + wm * 64 + (lg << 2);
  const int cb = n0 + wn * 64 + l15;
#pragma unroll
  for (int fg = 0; fg < 4; ++fg) {
    float gv[4];
#pragma unroll
    for (int r = 0; r < 4; ++r)
      gv[r] = gates[(size_t)(rb + fg * 16 + r) * NEXP + eidx];
#pragma unroll
    for (int j = 0; j < 4; ++j) {
      int col = cb + j * 16;
      float bv = bias[col];
#pragma unroll
      for (int r = 0; r < 4; ++r) {
        size_t o = (size_t)(rb + fg * 16 + r) * DOUT + col;
        float v = (acc[fg][j][r] + bv) * gv[r];
        outC[o] = accum ? outC[o] + v : v;
      }
    }
  }
}

// ---------------- gating head ----------------
__global__ __launch_bounds__(512)
void gating_head2(const unsigned short* __restrict__ gh,
                  const float* __restrict__ gW2,
                  const float* __restrict__ gb2,
                  float* __restrict__ gws,
                  float* __restrict__ g1,
                  float* __restrict__ g2) {
  __shared__ float wT[8][2048];
  const int t = threadIdx.x;
  for (int idx = t; idx < 16384; idx += 512) {
    wT[idx & 7][idx >> 3] = gW2[idx];
  }
  __syncthreads();
  const int wid = t >> 6, lane = t & 63;
  const int row = blockIdx.x * 8 + wid;
  const unsigned short* ghr = gh + (size_t)row * 2048;
  float s[8] = {0.f, 0.f, 0.f, 0.f, 0.f, 0.f, 0.f, 0.f};
#pragma unroll
  for (int j = 0; j < 8; ++j) {
    int k4 = lane + 64 * j;
    ushort4 hv = ((const ushort4*)ghr)[k4];
    float h0 = b2f(hv.x), h1 = b2f(hv.y), h2 = b2f(hv.z), h3 = b2f(hv.w);
#pragma unroll
    for (int e = 0; e < 8; ++e) {
      float4 w = ((const float4*)&wT[e][0])[k4];
      s[e] += h0 * w.x + h1 * w.y + h2 * w.z + h3 * w.w;
    }
  }
#pragma unroll
  for (int e = 0; e < 8; ++e)
#pragma unroll
    for (int off = 1; off < 64; off <<= 1) s[e] += __shfl_xor(s[e], off, 64);
  if (lane == 0) {
    float l[8], m = -1e30f;
#pragma unroll
    for (int e = 0; e < 8; ++e) {
      l[e] = s[e] + gb2[e];
      m = fmaxf(m, l[e]);
    }
    float sum = 0.f;
#pragma unroll
    for (int e = 0; e < 8; ++e) {
      l[e] = expf(l[e] - m);
      sum += l[e];
    }
    float inv = 1.f / sum;
#pragma unroll
    for (int e = 0; e < 8; ++e) {
      float gv = l[e] * inv;
      gws[(size_t)row * 8 + e] = gv;
      g1[(size_t)row * 8 + e] = gv;
      g2[(size_t)row * 8 + e] = gv;
    }
  }
}

extern "C" void kernel_launch(void* const* d_in, const int* in_sizes, int n_in,
                              void* d_out, int out_size, void* d_ws,
                              size_t ws_size, hipStream_t stream) {
  (void)in_sizes; (void)n_in; (void)out_size; (void)ws_size;
  const float* x   = (const float*)d_in[0];
  const float* gW1 = (const float*)d_in[1];
  const float* gb1 = (const float*)d_in[2];
  const float* gW2 = (const float*)d_in[3];
  const float* gb2 = (const float*)d_in[4];
  const float* eW1 = (const float*)d_in[5];
  const float* eb1 = (const float*)d_in[6];
  const float* eW2 = (const float*)d_in[7];
  const float* eb2 = (const float*)d_in[8];

  float* outC  = (float*)d_out;                       // [8192,1024]
  float* outG1 = outC + (size_t)BB * DOUT;            // [8192,8]
  float* outG2 = outG1 + (size_t)BB * NEXP;           // [8192,8]

  char* ws = (char*)d_ws;
  // layout: 100,925,440 B
  unsigned short* xb   = (unsigned short*)(ws);                 // 16 MB
  float*          gat  = (float*)(ws + 16777216);               // 256 KB
  unsigned short* w1T  = (unsigned short*)(ws + 17039360);      // 8 MB
  unsigned short* w2T  = (unsigned short*)(ws + 25427968);      // 8 MB
  unsigned short* hbuf = (unsigned short*)(ws + 33816576);      // 64 MB
  unsigned short* gh   = hbuf;                  // pre-loop alias (32 MB)
  unsigned short* gW1T = w1T;                   // pre-loop alias (4 MB)

  // x -> bf16
  cvt_f32_bf16<<<(BB * DIN / 4) / 256, 256, 0, stream>>>(x, xb, BB * DIN / 4);
  // gW1 -> gW1T
  trans_g<<<256, 512, 0, stream>>>(gW1, gW1T);
  // gating GEMM: gh = relu(x @ gW1 + gb1)   grid 256 (full chip)
  {
    GArgs a{xb, gW1T, DIN, DIN, GH_N, DIN, gb1, gh, 256};
    gemmU<<<256, 512, 0, stream>>>(a);
  }
  gating_head2<<<BB / 8, 512, 0, stream>>>(gh, gW2, gb2, gat, outG1, outG2);

  for (int e = 0; e < NEXP; ++e) {
    trans2<<<1024, 512, 0, stream>>>(
        eW1 + (size_t)e * DIN * DHID, w1T, eW2 + (size_t)e * DHID * DOUT, w2T);
    // G1: h = relu(x @ eW1_e + eb1_e)   grid 512 (2 exact rounds)
    {
      GArgs a{xb, w1T, DIN, DIN, DHID, DIN, eb1 + (size_t)e * DHID, hbuf, 512};
      gemmU<<<512, 512, 0, stream>>>(a);
    }
    // G2: outC (+)= gat[:,e]*(h @ eW2_e + eb2_e)   grid 256 (full chip)
    gemmF<<<256, 512, 0, stream>>>(hbuf, w2T, eb2 + (size_t)e * DOUT, outC,
                                   gat, e, e > 0 ? 1 : 0);
  }
}

// Round 13
// 1346.433 us; speedup vs baseline: 1.0516x; 1.0356x over previous
//
#include <hip/hip_runtime.h>
#include <hip/hip_bf16.h>
#include <stdint.h>

// B=8192, D_IN=1024, D_HID=4096, D_OUT=1024, E=8
#define BB 8192
#define DIN 1024
#define DHID 4096
#define DOUT 1024
#define NEXP 8
#define GH_N 2048  // D_HID/2

typedef __attribute__((ext_vector_type(8))) __bf16 bf16x8;
typedef __attribute__((ext_vector_type(4))) float f32x4;

__device__ inline unsigned short f2bf(float f) {
  unsigned u = __builtin_bit_cast(unsigned, f);
  u = (u + 0x7FFFu + ((u >> 16) & 1u)) >> 16;
  return (unsigned short)u;
}
__device__ inline float b2f(unsigned short s) {
  return __builtin_bit_cast(float, (unsigned)s << 16);
}

// ---------------- elementwise f32 -> bf16 ----------------
__global__ void cvt_f32_bf16(const float* __restrict__ in,
                             unsigned short* __restrict__ out, int n4) {
  int i = blockIdx.x * blockDim.x + threadIdx.x;
  if (i >= n4) return;
  float4 v = ((const float4*)in)[i];
  ushort4 o;
  o.x = f2bf(v.x); o.y = f2bf(v.y); o.z = f2bf(v.z); o.w = f2bf(v.w);
  ((ushort4*)out)[i] = o;
}

// ---- 128x64 transpose tile, 512 threads: full 256B read AND write segments
// in[R][C] f32, rows [by*128,+128) x cols [bx*64,+64)  ->  out[C][R] bf16
__device__ inline void tr128(const float* __restrict__ in,
                             unsigned short* __restrict__ out, int R, int C,
                             int bx, int by, int t) {
  __shared__ float tile[128][65];
  const int c0 = bx * 64, r0 = by * 128;
  const int tx = t & 63, ty = t >> 6;  // read: 64-lane rows, 8 rows/iter
#pragma unroll
  for (int i = 0; i < 16; ++i) {
    int r = i * 8 + ty;
    tile[r][tx] = in[(size_t)(r0 + r) * C + c0 + tx];
  }
  __syncthreads();
  const int tx2 = t & 127, ty2 = t >> 7;  // write: 128-lane rows (256B bf16)
#pragma unroll
  for (int i = 0; i < 16; ++i) {
    int cc = i * 4 + ty2;
    out[(size_t)(c0 + cc) * R + r0 + tx2] = f2bf(tile[tx2][cc]);
  }
}

// gW1 [1024][2048] -> gW1T [2048][1024]   (32 x 8 = 256 blocks)
__global__ __launch_bounds__(512)
void trans_g(const float* __restrict__ gW1, unsigned short* __restrict__ gW1T) {
  int b = blockIdx.x;
  tr128(gW1, gW1T, DIN, GH_N, b & 31, b >> 5, threadIdx.x);
}

// per-expert: eW1 [1024][4096]->w1T (64x8=512 blocks), eW2 [4096][1024]->w2T
// (16x32=512 blocks). grid 1024.
__global__ __launch_bounds__(512)
void trans2(const float* __restrict__ w1, unsigned short* __restrict__ w1T,
            const float* __restrict__ w2, unsigned short* __restrict__ w2T) {
  int b = blockIdx.x;
  if (b < 512) {
    tr128(w1, w1T, DIN, DHID, b & 63, b >> 6, threadIdx.x);
  } else {
    b -= 512;
    tr128(w2, w2T, DHID, DOUT, b & 15, b >> 4, threadIdx.x);
  }
}

// ---------------- async global->LDS 16B ----------------
__device__ inline void gload16(const void* g, void* l) {
  __builtin_amdgcn_global_load_lds(
      (const __attribute__((address_space(1))) void*)g,
      (__attribute__((address_space(3))) void*)l, 16, 0, 0);
}

template <int N>
__device__ inline void waitv() {
  if constexpr (N == 0) asm volatile("s_waitcnt vmcnt(0)" ::: "memory");
  else if constexpr (N == 2) asm volatile("s_waitcnt vmcnt(2)" ::: "memory");
  else if constexpr (N == 4) asm volatile("s_waitcnt vmcnt(4)" ::: "memory");
  else if constexpr (N == 6) asm volatile("s_waitcnt vmcnt(6)" ::: "memory");
  else asm volatile("s_waitcnt vmcnt(0)" ::: "memory");
}
__device__ inline void waitlgkm0() {
  asm volatile("s_waitcnt lgkmcnt(0)" ::: "memory");
  __builtin_amdgcn_sched_barrier(0);
}
__device__ inline bf16x8 ldr(const char* p) { return *(const bf16x8*)p; }

// ---------------- gemmU: 256x256 fat 4-phase (proven ~1270 TF) -------------
// C = A[8192,K]*Bt[N,K]^T, epi: outb = bf16(relu(acc+bias[col]))
struct GArgs {
  const unsigned short* A;
  const unsigned short* Bt;
  int lda, ldb, N, K;
  const float* bias;
  unsigned short* outb;
  int nb;
};

__global__ __launch_bounds__(512, 2)
void gemmU(GArgs g) {
  __shared__ char lds[131072];
  char* Als = lds;
  char* Bls = lds + 65536;
  constexpr int ABYTES = 32768, BBYTES = 32768;
  const int t = threadIdx.x;
  const int lane = t & 63;
  const int wid = t >> 6;
  const int wm = wid >> 2;
  const int wn = wid & 3;
  const int l15 = lane & 15, lg = lane >> 4;

  const int nb = g.nb;
  const int local = blockIdx.x;
  const int swz = (local & 7) * (nb >> 3) + (local >> 3);
  const int nbn = g.N >> 8;
  const int bn = swz % nbn, bm = swz / nbn;
  const int m0 = bm * 256, n0 = bn * 256;

  const int prow = t >> 3;
  const int cOff = ((t & 7) ^ (prow & 7)) * 8;
  const unsigned short* aP[4];
  const unsigned short* bP[4];
#pragma unroll
  for (int u = 0; u < 4; ++u) {
    int p = u * 64 + prow;
    int ga = ((p >> 6) & 1) * 128 + ((p >> 7) & 1) * 64 + (p & 63);
    aP[u] = g.A + (size_t)(m0 + ga) * g.lda + cOff;
    int gb = ((p >> 5) & 3) * 64 + ((p >> 7) & 1) * 32 + (p & 31);
    bP[u] = g.Bt + (size_t)(n0 + gb) * g.ldb + cOff;
  }
  const int ldst = t * 16;

  const int slot0 = ((lg) ^ (l15 & 7)) * 16;
  const int slot1 = ((4 + lg) ^ (l15 & 7)) * 16;
  const int aRB0 = (wm * 64 + l15) * 128;
  const int aRB1 = (128 + wm * 64 + l15) * 128;
  const int bCB0 = (wn * 32 + l15) * 128;
  const int bCB1 = (128 + wn * 32 + l15) * 128;

  f32x4 acc[8][4];
  const f32x4 zero = {0.f, 0.f, 0.f, 0.f};
#pragma unroll
  for (int i = 0; i < 8; ++i)
#pragma unroll
    for (int j = 0; j < 4; ++j) acc[i][j] = zero;

  bf16x8 ar[4][2], bc0[2][2], bc1[2][2];
  const int NT = g.K >> 6;

  gload16(bP[0], Bls + 0 * 8192 + ldst);
  gload16(bP[1], Bls + 1 * 8192 + ldst);
  gload16(aP[0], Als + 0 * 8192 + ldst);
  gload16(aP[1], Als + 1 * 8192 + ldst);
  gload16(bP[2], Bls + 2 * 8192 + ldst);
  gload16(bP[3], Bls + 3 * 8192 + ldst);
  gload16(aP[2], Als + 2 * 8192 + ldst);
  gload16(aP[3], Als + 3 * 8192 + ldst);
  waitv<4>();
  __builtin_amdgcn_s_barrier();

  for (int T = 0; T < NT; ++T) {
    const int buf = T & 1;
    const char* Ab = Als + buf * ABYTES;
    const char* Bb = Bls + buf * BBYTES;
    char* An = Als + (buf ^ 1) * ABYTES;
    char* Bn = Bls + (buf ^ 1) * BBYTES;
    const bool stg = (T + 1 < NT);
    const int kn = (T + 1) << 6;

    // ph0
#pragma unroll
    for (int f = 0; f < 4; ++f) {
      ar[f][0] = ldr(Ab + aRB0 + f * 2048 + slot0);
      ar[f][1] = ldr(Ab + aRB0 + f * 2048 + slot1);
    }
#pragma unroll
    for (int c = 0; c < 2; ++c) {
      bc0[c][0] = ldr(Bb + bCB0 + c * 2048 + slot0);
      bc0[c][1] = ldr(Bb + bCB0 + c * 2048 + slot1);
    }
    if (stg) {
      gload16(bP[0] + kn, Bn + 0 * 8192 + ldst);
      gload16(bP[1] + kn, Bn + 1 * 8192 + ldst);
    }
    __builtin_amdgcn_s_barrier();
    waitlgkm0();
    __builtin_amdgcn_s_setprio(1);
#pragma unroll
    for (int ksl = 0; ksl < 2; ++ksl)
#pragma unroll
      for (int f = 0; f < 4; ++f)
#pragma unroll
        for (int c = 0; c < 2; ++c)
          acc[f][c] = __builtin_amdgcn_mfma_f32_16x16x32_bf16(
              ar[f][ksl], bc0[c][ksl], acc[f][c], 0, 0, 0);
    __builtin_amdgcn_s_setprio(0);
    if (stg) waitv<4>(); else waitv<2>();
    __builtin_amdgcn_s_barrier();

    // ph1
#pragma unroll
    for (int c = 0; c < 2; ++c) {
      bc1[c][0] = ldr(Bb + bCB1 + c * 2048 + slot0);
      bc1[c][1] = ldr(Bb + bCB1 + c * 2048 + slot1);
    }
    if (stg) {
      gload16(aP[0] + kn, An + 0 * 8192 + ldst);
      gload16(aP[1] + kn, An + 1 * 8192 + ldst);
    }
    __builtin_amdgcn_s_barrier();
    waitlgkm0();
    __builtin_amdgcn_s_setprio(1);
#pragma unroll
    for (int ksl = 0; ksl < 2; ++ksl)
#pragma unroll
      for (int f = 0; f < 4; ++f)
#pragma unroll
        for (int c = 0; c < 2; ++c)
          acc[f][2 + c] = __builtin_amdgcn_mfma_f32_16x16x32_bf16(
              ar[f][ksl], bc1[c][ksl], acc[f][2 + c], 0, 0, 0);
    __builtin_amdgcn_s_setprio(0);
    if (stg) waitv<4>(); else waitv<0>();
    __builtin_amdgcn_s_barrier();

    // ph2
#pragma unroll
    for (int f = 0; f < 4; ++f) {
      ar[f][0] = ldr(Ab + aRB1 + f * 2048 + slot0);
      ar[f][1] = ldr(Ab + aRB1 + f * 2048 + slot1);
    }
    if (stg) {
      gload16(bP[2] + kn, Bn + 2 * 8192 + ldst);
      gload16(bP[3] + kn, Bn + 3 * 8192 + ldst);
    }
    __builtin_amdgcn_s_barrier();
    waitlgkm0();
    __builtin_amdgcn_s_setprio(1);
#pragma unroll
    for (int ksl = 0; ksl < 2; ++ksl)
#pragma unroll
      for (int f = 0; f < 4; ++f)
#pragma unroll
        for (int c = 0; c < 2; ++c)
          acc[4 + f][2 + c] = __builtin_amdgcn_mfma_f32_16x16x32_bf16(
              ar[f][ksl], bc1[c][ksl], acc[4 + f][2 + c], 0, 0, 0);
    __builtin_amdgcn_s_setprio(0);
    __builtin_amdgcn_s_barrier();

    // ph3
    if (stg) {
      gload16(aP[2] + kn, An + 2 * 8192 + ldst);
      gload16(aP[3] + kn, An + 3 * 8192 + ldst);
    }
    __builtin_amdgcn_s_barrier();
    __builtin_amdgcn_s_setprio(1);
#pragma unroll
    for (int ksl = 0; ksl < 2; ++ksl)
#pragma unroll
      for (int f = 0; f < 4; ++f)
#pragma unroll
        for (int c = 0; c < 2; ++c)
          acc[4 + f][c] = __builtin_amdgcn_mfma_f32_16x16x32_bf16(
              ar[f][ksl], bc0[c][ksl], acc[4 + f][c], 0, 0, 0);
    __builtin_amdgcn_s_setprio(0);
    if (stg) waitv<4>();
    __builtin_amdgcn_s_barrier();
  }

  const int rb = m0 + wm * 128 + (lg << 2);
  const int cb = n0 + wn * 64 + l15;
  const int N = g.N;
#pragma unroll
  for (int fg = 0; fg < 8; ++fg) {
#pragma unroll
    for (int j = 0; j < 4; ++j) {
      int col = cb + j * 16;
      float bv = g.bias[col];
#pragma unroll
      for (int r = 0; r < 4; ++r) {
        int row = rb + fg * 16 + r;
        float v = acc[fg][j][r] + bv;
        g.outb[(size_t)row * N + col] = f2bf(fmaxf(v, 0.f));
      }
    }
  }
}

// ---------------- gemmF: G2 engine (128x256, 2 fat phases, 3-buf ring) -----
// No K-skew: all blocks stream the same hbuf k-tile in lockstep -> L3 serves
// each line once (FETCH = compulsory 82 MB; r12 skew proved 3.3x fetch blowup)
__global__ __launch_bounds__(512)
void gemmF(const unsigned short* __restrict__ A,
           const unsigned short* __restrict__ Bt,
           const float* __restrict__ bias,
           float* __restrict__ outC,
           const float* __restrict__ gates, int eidx, int accum) {
  constexpr int SLOT = 49152;
  __shared__ char lds[3 * SLOT];
  const int t = threadIdx.x;
  const int lane = t & 63;
  const int wid = t >> 6;
  const int wm = wid >> 2;
  const int wn = wid & 3;
  const int l15 = lane & 15, lg = lane >> 4;

  const int local = blockIdx.x;
  const int swz = (local & 7) * 32 + (local >> 3);
  const int bn = swz & 3, bm = swz >> 2;
  const int m0 = bm * 128, n0 = bn * 256;

  const int prow = t >> 3;
  const int cOff = ((t & 7) ^ (prow & 7)) * 8;
  const unsigned short* aP[2];
  const unsigned short* bP[4];
#pragma unroll
  for (int u = 0; u < 2; ++u)
    aP[u] = A + (size_t)(m0 + u * 64 + prow) * DHID + cOff;
#pragma unroll
  for (int u = 0; u < 4; ++u) {
    int p = u * 64 + prow;
    int gb = ((p >> 5) & 3) * 64 + ((p >> 7) & 1) * 32 + (p & 31);
    bP[u] = Bt + (size_t)(n0 + gb) * DHID + cOff;
  }
  const int ldst = t * 16;

  const int slot0 = ((lg) ^ (l15 & 7)) * 16;
  const int slot1 = ((4 + lg) ^ (l15 & 7)) * 16;
  const int aRB = (wm * 64 + l15) * 128;
  const int bCB0 = 16384 + (wn * 32 + l15) * 128;
  const int bCB1 = 16384 + (128 + wn * 32 + l15) * 128;

  f32x4 acc[4][4];
  const f32x4 zero = {0.f, 0.f, 0.f, 0.f};
#pragma unroll
  for (int i = 0; i < 4; ++i)
#pragma unroll
    for (int j = 0; j < 4; ++j) acc[i][j] = zero;

  bf16x8 af[2][2], bc[4][2];
  const int NT = DHID >> 6;  // 64

#pragma unroll
  for (int T0 = 0; T0 < 2; ++T0) {
    char* S = lds + T0 * SLOT;
    const int k0 = T0 << 6;
    gload16(aP[0] + k0, S + 0 * 8192 + ldst);
    gload16(aP[1] + k0, S + 1 * 8192 + ldst);
    gload16(bP[0] + k0, S + 16384 + 0 * 8192 + ldst);
    gload16(bP[1] + k0, S + 16384 + 1 * 8192 + ldst);
    gload16(bP[2] + k0, S + 16384 + 2 * 8192 + ldst);
    gload16(bP[3] + k0, S + 16384 + 3 * 8192 + ldst);
  }
  waitv<6>();
  __builtin_amdgcn_s_barrier();

  for (int T = 0; T < NT; ++T) {
    const char* Sb = lds + (T % 3) * SLOT;
    char* Sn = lds + ((T + 2) % 3) * SLOT;
    const bool stg = (T + 2 < NT);
    const int kn = (T + 2) << 6;

    // ph0
#pragma unroll
    for (int f = 0; f < 2; ++f) {
      af[f][0] = ldr(Sb + aRB + f * 2048 + slot0);
      af[f][1] = ldr(Sb + aRB + f * 2048 + slot1);
    }
#pragma unroll
    for (int c = 0; c < 2; ++c) {
      bc[c][0] = ldr(Sb + bCB0 + c * 2048 + slot0);
      bc[c][1] = ldr(Sb + bCB0 + c * 2048 + slot1);
      bc[2 + c][0] = ldr(Sb + bCB1 + c * 2048 + slot0);
      bc[2 + c][1] = ldr(Sb + bCB1 + c * 2048 + slot1);
    }
    if (stg) {
      gload16(aP[0] + kn, Sn + 0 * 8192 + ldst);
      gload16(aP[1] + kn, Sn + 1 * 8192 + ldst);
      gload16(bP[0] + kn, Sn + 16384 + 0 * 8192 + ldst);
    }
    __builtin_amdgcn_s_barrier();
    waitlgkm0();
    __builtin_amdgcn_s_setprio(1);
#pragma unroll
    for (int ksl = 0; ksl < 2; ++ksl)
#pragma unroll
      for (int f = 0; f < 2; ++f)
#pragma unroll
        for (int c = 0; c < 4; ++c)
          acc[f][c] = __builtin_amdgcn_mfma_f32_16x16x32_bf16(
              af[f][ksl], bc[c][ksl], acc[f][c], 0, 0, 0);
    __builtin_amdgcn_s_setprio(0);
    __builtin_amdgcn_s_barrier();

    // ph1
#pragma unroll
    for (int f = 0; f < 2; ++f) {
      af[f][0] = ldr(Sb + aRB + (2 + f) * 2048 + slot0);
      af[f][1] = ldr(Sb + aRB + (2 + f) * 2048 + slot1);
    }
    if (stg) {
      gload16(bP[1] + kn, Sn + 16384 + 1 * 8192 + ldst);
      gload16(bP[2] + kn, Sn + 16384 + 2 * 8192 + ldst);
      gload16(bP[3] + kn, Sn + 16384 + 3 * 8192 + ldst);
    }
    __builtin_amdgcn_s_barrier();
    waitlgkm0();
    __builtin_amdgcn_s_setprio(1);
#pragma unroll
    for (int ksl = 0; ksl < 2; ++ksl)
#pragma unroll
      for (int f = 0; f < 2; ++f)
#pragma unroll
        for (int c = 0; c < 4; ++c)
          acc[2 + f][c] = __builtin_amdgcn_mfma_f32_16x16x32_bf16(
              af[f][ksl], bc[c][ksl], acc[2 + f][c], 0, 0, 0);
    __builtin_amdgcn_s_setprio(0);
    if (stg) waitv<6>();
    else if (T + 1 < NT) waitv<0>();
    __builtin_amdgcn_s_barrier();
  }

  const int rb = m0 + wm * 64 + (lg << 2);
  const int cb = n0 + wn * 64 + l15;
#pragma unroll
  for (int fg = 0; fg < 4; ++fg) {
    float gv[4];
#pragma unroll
    for (int r = 0; r < 4; ++r)
      gv[r] = gates[(size_t)(rb + fg * 16 + r) * NEXP + eidx];
#pragma unroll
    for (int j = 0; j < 4; ++j) {
      int col = cb + j * 16;
      float bv = bias[col];
#pragma unroll
      for (int r = 0; r < 4; ++r) {
        size_t o = (size_t)(rb + fg * 16 + r) * DOUT + col;
        float v = (acc[fg][j][r] + bv) * gv[r];
        outC[o] = accum ? outC[o] + v : v;
      }
    }
  }
}

// ---------------- gating head ----------------
__global__ __launch_bounds__(512)
void gating_head2(const unsigned short* __restrict__ gh,
                  const float* __restrict__ gW2,
                  const float* __restrict__ gb2,
                  float* __restrict__ gws,
                  float* __restrict__ g1,
                  float* __restrict__ g2) {
  __shared__ float wT[8][2048];
  const int t = threadIdx.x;
  for (int idx = t; idx < 16384; idx += 512) {
    wT[idx & 7][idx >> 3] = gW2[idx];
  }
  __syncthreads();
  const int wid = t >> 6, lane = t & 63;
  const int row = blockIdx.x * 8 + wid;
  const unsigned short* ghr = gh + (size_t)row * 2048;
  float s[8] = {0.f, 0.f, 0.f, 0.f, 0.f, 0.f, 0.f, 0.f};
#pragma unroll
  for (int j = 0; j < 8; ++j) {
    int k4 = lane + 64 * j;
    ushort4 hv = ((const ushort4*)ghr)[k4];
    float h0 = b2f(hv.x), h1 = b2f(hv.y), h2 = b2f(hv.z), h3 = b2f(hv.w);
#pragma unroll
    for (int e = 0; e < 8; ++e) {
      float4 w = ((const float4*)&wT[e][0])[k4];
      s[e] += h0 * w.x + h1 * w.y + h2 * w.z + h3 * w.w;
    }
  }
#pragma unroll
  for (int e = 0; e < 8; ++e)
#pragma unroll
    for (int off = 1; off < 64; off <<= 1) s[e] += __shfl_xor(s[e], off, 64);
  if (lane == 0) {
    float l[8], m = -1e30f;
#pragma unroll
    for (int e = 0; e < 8; ++e) {
      l[e] = s[e] + gb2[e];
      m = fmaxf(m, l[e]);
    }
    float sum = 0.f;
#pragma unroll
    for (int e = 0; e < 8; ++e) {
      l[e] = expf(l[e] - m);
      sum += l[e];
    }
    float inv = 1.f / sum;
#pragma unroll
    for (int e = 0; e < 8; ++e) {
      float gv = l[e] * inv;
      gws[(size_t)row * 8 + e] = gv;
      g1[(size_t)row * 8 + e] = gv;
      g2[(size_t)row * 8 + e] = gv;
    }
  }
}

extern "C" void kernel_launch(void* const* d_in, const int* in_sizes, int n_in,
                              void* d_out, int out_size, void* d_ws,
                              size_t ws_size, hipStream_t stream) {
  (void)in_sizes; (void)n_in; (void)out_size; (void)ws_size;
  const float* x   = (const float*)d_in[0];
  const float* gW1 = (const float*)d_in[1];
  const float* gb1 = (const float*)d_in[2];
  const float* gW2 = (const float*)d_in[3];
  const float* gb2 = (const float*)d_in[4];
  const float* eW1 = (const float*)d_in[5];
  const float* eb1 = (const float*)d_in[6];
  const float* eW2 = (const float*)d_in[7];
  const float* eb2 = (const float*)d_in[8];

  float* outC  = (float*)d_out;                       // [8192,1024]
  float* outG1 = outC + (size_t)BB * DOUT;            // [8192,8]
  float* outG2 = outG1 + (size_t)BB * NEXP;           // [8192,8]

  char* ws = (char*)d_ws;
  // layout: 100,925,440 B
  unsigned short* xb   = (unsigned short*)(ws);                 // 16 MB
  float*          gat  = (float*)(ws + 16777216);               // 256 KB
  unsigned short* w1T  = (unsigned short*)(ws + 17039360);      // 8 MB
  unsigned short* w2T  = (unsigned short*)(ws + 25427968);      // 8 MB
  unsigned short* hbuf = (unsigned short*)(ws + 33816576);      // 64 MB
  unsigned short* gh   = hbuf;                  // pre-loop alias (32 MB)
  unsigned short* gW1T = w1T;                   // pre-loop alias (4 MB)

  // x -> bf16
  cvt_f32_bf16<<<(BB * DIN / 4) / 256, 256, 0, stream>>>(x, xb, BB * DIN / 4);
  // gW1 -> gW1T
  trans_g<<<256, 512, 0, stream>>>(gW1, gW1T);
  // gating GEMM: gh = relu(x @ gW1 + gb1)   grid 256 (full chip)
  {
    GArgs a{xb, gW1T, DIN, DIN, GH_N, DIN, gb1, gh, 256};
    gemmU<<<256, 512, 0, stream>>>(a);
  }
  gating_head2<<<BB / 8, 512, 0, stream>>>(gh, gW2, gb2, gat, outG1, outG2);

  for (int e = 0; e < NEXP; ++e) {
    trans2<<<1024, 512, 0, stream>>>(
        eW1 + (size_t)e * DIN * DHID, w1T, eW2 + (size_t)e * DHID * DOUT, w2T);
    // G1: h = relu(x @ eW1_e + eb1_e)   grid 512 (2 exact rounds)
    {
      GArgs a{xb, w1T, DIN, DIN, DHID, DIN, eb1 + (size_t)e * DHID, hbuf, 512};
      gemmU<<<512, 512, 0, stream>>>(a);
    }
    // G2: outC (+)= gat[:,e]*(h @ eW2_e + eb2_e)   grid 256 (full chip)
    gemmF<<<256, 512, 0, stream>>>(hbuf, w2T, eb2 + (size_t)e * DOUT, outC,
                                   gat, e, e > 0 ? 1 : 0);
  }
}